// Round 5
// baseline (221.154 us; speedup 1.0000x reference)
//
#include <hip/hip_runtime.h>

#define DEV static __device__ __forceinline__

typedef float f32x4 __attribute__((ext_vector_type(4)));
typedef __bf16 bf16x8 __attribute__((ext_vector_type(8)));
typedef unsigned short u16x8 __attribute__((ext_vector_type(8)));
typedef unsigned short u16x4 __attribute__((ext_vector_type(4)));

#define MFMA(a, b, c) __builtin_amdgcn_mfma_f32_16x16x32_bf16((a), (b), (c), 0, 0, 0)

// B=8, T=2048, C=1024, H=64
#define TT 2048
#define CE 1024
#define HS 64

// ws layout (ushort elements unless noted)
#define WBT_E 0                   // [3][64 n][1024 k] bf16 (Wq scaled by log2e/32)
#define Q_E   196608              // [B*T][64] bf16
#define K_E   (Q_E + 1048576)
#define VT_E  (K_E + 1048576)     // [B][64 h][2048 t] bf16
#define PO_E  (VT_E + 1048576)    // [4096 slots][16 row][64 h] bf16 partial O^T
#define PML_E (PO_E + 4194304)    // float [4096][16 row][2] {m,l}
#define BIAS_E (PML_E + 262144)   // float [B*T] pad bias (0 or -1e30)

DEV unsigned short cvt_bf16(float f) {
    unsigned int u = __builtin_bit_cast(unsigned int, f);
    u += 0x7FFFu + ((u >> 16) & 1u);   // RNE (finite inputs)
    return (unsigned short)(u >> 16);
}

DEV float bf2f(unsigned short v) {
    unsigned int u = ((unsigned int)v) << 16;
    return __builtin_bit_cast(float, u);
}

DEV bf16x8 ld_bf8(const unsigned short* p) {
    union { u16x8 u; bf16x8 b; } v;
    v.u = *(const u16x8*)p;
    return v.b;
}

DEV bf16x8 as_bf8(u16x8 u) {
    union { u16x8 u; bf16x8 b; } v;
    v.u = u;
    return v.b;
}

// ---------------- kernel 1: W fp32 -> bf16 transposed [n][k] ----------------
__global__ __launch_bounds__(256) void wconv_kernel(
        const float* __restrict__ Wq, const float* __restrict__ Wk,
        const float* __restrict__ Wv, unsigned short* __restrict__ wbt) {
    __shared__ unsigned short Tr[64 * 72];
    const int blk = blockIdx.x;
    const int head = blk >> 4, kt = blk & 15;
    const int k0 = kt * 64;
    const float* W = (head == 0) ? Wq : ((head == 1) ? Wk : Wv);
    const float sc = (head == 0) ? 0.045084220027780106f : 1.0f;  // log2(e)/32
    const int t = threadIdx.x;
    const int rrow = t >> 4, c4 = (t & 15) * 4;
    for (int i = 0; i < 4; ++i) {
        int krow = rrow + i * 16;
        f32x4 f = *(const f32x4*)(W + (size_t)(k0 + krow) * 64 + c4);
        Tr[(c4 + 0) * 72 + krow] = cvt_bf16(f[0] * sc);
        Tr[(c4 + 1) * 72 + krow] = cvt_bf16(f[1] * sc);
        Tr[(c4 + 2) * 72 + krow] = cvt_bf16(f[2] * sc);
        Tr[(c4 + 3) * 72 + krow] = cvt_bf16(f[3] * sc);
    }
    __syncthreads();
    const int n = t >> 2, off = (t & 3) * 16;
    u16x8 a0 = *(const u16x8*)&Tr[n * 72 + off];
    u16x8 a1 = *(const u16x8*)&Tr[n * 72 + off + 8];
    unsigned short* dst = wbt + head * 65536 + n * 1024 + k0 + off;
    *(u16x8*)dst = a0;
    *(u16x8*)(dst + 8) = a1;
}

// ---------------- kernel 1b: pad mask -> additive float bias ----------------
__global__ __launch_bounds__(256) void bias_kernel(
        const int* __restrict__ pm, float* __restrict__ biasf) {
    int i = blockIdx.x * 256 + threadIdx.x;   // < 16384
    biasf[i] = pm[i] ? 0.0f : -1e30f;
}

// ---------------- kernel 2: projection q,k = x@W; v transposed -> vt --------
// 512 blocks x 4 waves. 32 rows/block; wave w -> cols w*48..+47.
// NO LDS staging, NO K-loop barriers: x A-frags and W B-frags load direct
// global->register (x lines shared via L1 across the 4 waves), 1-step
// register prefetch. Single barrier in the v-transpose epilogue.
__global__ __launch_bounds__(256) void proj_kernel(
        const float* __restrict__ x, const unsigned short* __restrict__ wbt,
        unsigned short* __restrict__ qws, unsigned short* __restrict__ kws,
        unsigned short* __restrict__ vtws) {
    __shared__ __align__(16) unsigned short TT2[64 * 48];  // v-transpose scratch

    const int t = threadIdx.x;
    const int lane = t & 63, w = t >> 6;
    const int quad = lane >> 4, c = lane & 15;
    const int t0 = blockIdx.x * 32;

    const float* xb[2];
    xb[0] = x + (size_t)(t0 + c) * CE + quad * 8;
    xb[1] = x + (size_t)(t0 + 16 + c) * CE + quad * 8;
    const unsigned short* wbase = wbt + (size_t)(w * 48 + c) * 1024 + quad * 8;

    f32x4 acc[2][3] = {};
    f32x4 xa[2][2][2], xn[2][2][2];
    u16x8 wc[3][2], wn[3][2];

    // prologue: load step 0
#pragma unroll
    for (int mt = 0; mt < 2; ++mt)
#pragma unroll
        for (int kk = 0; kk < 2; ++kk) {
            xa[mt][kk][0] = *(const f32x4*)(xb[mt] + kk * 32);
            xa[mt][kk][1] = *(const f32x4*)(xb[mt] + kk * 32 + 4);
        }
#pragma unroll
    for (int nt = 0; nt < 3; ++nt)
#pragma unroll
        for (int kk = 0; kk < 2; ++kk)
            wc[nt][kk] = *(const u16x8*)(wbase + nt * 16384 + kk * 32);

    for (int step = 0; step < 16; ++step) {
        const int ksn = ((step + 1) & 15) * 64;   // wraps on last step (discarded)
        // ---- prefetch step+1 ----
#pragma unroll
        for (int mt = 0; mt < 2; ++mt)
#pragma unroll
            for (int kk = 0; kk < 2; ++kk) {
                xn[mt][kk][0] = *(const f32x4*)(xb[mt] + ksn + kk * 32);
                xn[mt][kk][1] = *(const f32x4*)(xb[mt] + ksn + kk * 32 + 4);
            }
#pragma unroll
        for (int nt = 0; nt < 3; ++nt)
#pragma unroll
            for (int kk = 0; kk < 2; ++kk)
                wn[nt][kk] = *(const u16x8*)(wbase + nt * 16384 + ksn + kk * 32);
        // ---- compute current step ----
#pragma unroll
        for (int kk = 0; kk < 2; ++kk) {
            u16x8 ap[2];
#pragma unroll
            for (int mt = 0; mt < 2; ++mt)
#pragma unroll
                for (int j = 0; j < 4; ++j) {
                    ap[mt][j] = cvt_bf16(xa[mt][kk][0][j]);
                    ap[mt][4 + j] = cvt_bf16(xa[mt][kk][1][j]);
                }
#pragma unroll
            for (int nt = 0; nt < 3; ++nt) {
                bf16x8 bb = as_bf8(wc[nt][kk]);
                acc[0][nt] = MFMA(as_bf8(ap[0]), bb, acc[0][nt]);
                acc[1][nt] = MFMA(as_bf8(ap[1]), bb, acc[1][nt]);
            }
        }
        // rotate
#pragma unroll
        for (int mt = 0; mt < 2; ++mt)
#pragma unroll
            for (int kk = 0; kk < 2; ++kk) {
                xa[mt][kk][0] = xn[mt][kk][0];
                xa[mt][kk][1] = xn[mt][kk][1];
            }
#pragma unroll
        for (int nt = 0; nt < 3; ++nt)
#pragma unroll
            for (int kk = 0; kk < 2; ++kk) wc[nt][kk] = wn[nt][kk];
    }

    // epilogue: q,k direct; v transposed via LDS (64 h x 32 t, stride 48)
    for (int mt = 0; mt < 2; ++mt)
        for (int nt = 0; nt < 3; ++nt) {
            f32x4 a = acc[mt][nt];
            int col = w * 48 + nt * 16 + c;
            for (int r = 0; r < 4; ++r) {
                int row = mt * 16 + quad * 4 + r;
                size_t tg = (size_t)(t0 + row);
                unsigned short hv = cvt_bf16(a[r]);
                if (col < 64)       qws[tg * HS + col] = hv;
                else if (col < 128) kws[tg * HS + col - 64] = hv;
                else                TT2[(col - 128) * 48 + row] = hv;
            }
        }
    __syncthreads();
    {
        int h = t >> 2, off = (t & 3) * 8;
        u16x8 v = *(const u16x8*)&TT2[h * 48 + off];
        int b = t0 >> 11, tl0 = t0 & 2047;
        *(u16x8*)(vtws + (size_t)(b * 64 + h) * TT + tl0 + off) = v;
    }
}

// ---------------- kernel 3: flash partial, S-TRANSPOSED formulation ---------
// grid 4096: b=blk>>9, qt=(blk>>2)&127 (16 q-rows), sp=blk&3 (512-kv split).
// 1 wave/block, no barriers. S^T = K·Q^T so lane c owns q-row (qt*16+c):
// softmax = in-lane tree + 2 shfls, scalar m/l/alpha. O^T = V^T·P^T.
// 64-kv chunks; K prefetched 1 chunk ahead; pad mask via additive bias.
__global__ __launch_bounds__(64) void flash_kernel(
        const unsigned short* __restrict__ qws, const unsigned short* __restrict__ kws,
        const unsigned short* __restrict__ vtws, const float* __restrict__ biasf,
        unsigned short* __restrict__ pO, float* __restrict__ pml) {
    __shared__ __align__(16) unsigned short Ps[16 * 72];  // P [qrow][kv64]

    const int blk = blockIdx.x;
    const int sp = blk & 3, qt = (blk >> 2) & 127, b = blk >> 9;
    const int ns = (qt >> 5) + 1;                 // ceil((qt+1)*16 / 512)
    if (sp >= ns) return;
    const int kvlen = qt * 16 + 16;
    const int kvs = sp * 512;
    const int kve = (kvs + 512 < kvlen) ? kvs + 512 : kvlen;
    const int nch = (kve - kvs + 63) >> 6;
    const bool diag = (sp == ns - 1);
    const int lane = threadIdx.x;
    const int quad = lane >> 4, c = lane & 15;

    const unsigned short* kbase = kws + (size_t)(b * TT + c) * HS + quad * 8;
    const unsigned short* vbase = vtws + (size_t)(b * 64 + c) * TT + quad * 8;
    const float* bbase = biasf + b * TT + quad * 4;

    // Q B-frag (n = qrow = c, k = kk*32 + quad*8 + j)
    bf16x8 qf[2];
#pragma unroll
    for (int kk = 0; kk < 2; ++kk)
        qf[kk] = ld_bf8(qws + (size_t)(b * TT + qt * 16 + c) * HS + kk * 32 + quad * 8);

    // K A-frags (m = kv row), prefetch chunk 0
    u16x8 kc[4][2], kn[4][2], vc[4][2];
#pragma unroll
    for (int nt = 0; nt < 4; ++nt)
#pragma unroll
        for (int kk = 0; kk < 2; ++kk)
            kc[nt][kk] = *(const u16x8*)(kbase + (size_t)(kvs + nt * 16) * HS + kk * 32);

    f32x4 o[4] = {};
    float m_run = -1e30f, l_run = 0.0f;

    for (int ch = 0; ch < nch; ++ch) {
        const int kv0 = kvs + ch * 64;
        const int kvn = (ch + 1 < nch) ? kv0 + 64 : kv0;   // last: dummy reload
        // ---- V current chunk (used at end -> long slack) ----
#pragma unroll
        for (int ht = 0; ht < 4; ++ht)
#pragma unroll
            for (int kx = 0; kx < 2; ++kx)
                vc[ht][kx] = *(const u16x8*)(vbase + (size_t)(ht * 16) * TT + kv0 + kx * 32);
        // ---- bias (pad mask) ----
        f32x4 bv[4];
#pragma unroll
        for (int nt = 0; nt < 4; ++nt)
            bv[nt] = *(const f32x4*)(bbase + kv0 + nt * 16);
        // ---- K next-chunk prefetch ----
#pragma unroll
        for (int nt = 0; nt < 4; ++nt)
#pragma unroll
            for (int kk = 0; kk < 2; ++kk)
                kn[nt][kk] = *(const u16x8*)(kbase + (size_t)(kvn + nt * 16) * HS + kk * 32);

        // ---- S^T = K Q^T : tile nt rows kv0+nt*16+quad*4+r, col qrow=c ----
        f32x4 s4[4] = {};
#pragma unroll
        for (int kk = 0; kk < 2; ++kk)
#pragma unroll
            for (int nt = 0; nt < 4; ++nt)
                s4[nt] = MFMA(as_bf8(kc[nt][kk]), qf[kk], s4[nt]);

        // ---- mask ----
        if (diag && ch == nch - 1) {
            const int qrow = qt * 16 + c;
#pragma unroll
            for (int nt = 0; nt < 4; ++nt)
#pragma unroll
                for (int r = 0; r < 4; ++r) {
                    int kv = kv0 + nt * 16 + quad * 4 + r;
                    s4[nt][r] = (kv > qrow) ? -1e30f : (s4[nt][r] + bv[nt][r]);
                }
        } else {
#pragma unroll
            for (int nt = 0; nt < 4; ++nt)
#pragma unroll
                for (int r = 0; r < 4; ++r) s4[nt][r] += bv[nt][r];
        }

        // ---- online softmax: in-lane tree + 2 shfls, scalar state ----
        float mnt[4];
#pragma unroll
        for (int nt = 0; nt < 4; ++nt)
            mnt[nt] = fmaxf(fmaxf(s4[nt][0], s4[nt][1]), fmaxf(s4[nt][2], s4[nt][3]));
        float mx = fmaxf(fmaxf(mnt[0], mnt[1]), fmaxf(mnt[2], mnt[3]));
        mx = fmaxf(mx, __shfl_xor(mx, 16, 64));
        mx = fmaxf(mx, __shfl_xor(mx, 32, 64));
        float mnew = fmaxf(m_run, mx);
        float al = exp2f(m_run - mnew);
        m_run = mnew;
#pragma unroll
        for (int nt = 0; nt < 4; ++nt)
#pragma unroll
            for (int r = 0; r < 4; ++r) s4[nt][r] = exp2f(s4[nt][r] - mnew);
        float snt[4];
#pragma unroll
        for (int nt = 0; nt < 4; ++nt)
            snt[nt] = (s4[nt][0] + s4[nt][1]) + (s4[nt][2] + s4[nt][3]);
        float rs = (snt[0] + snt[1]) + (snt[2] + snt[3]);
        rs += __shfl_xor(rs, 16, 64);
        rs += __shfl_xor(rs, 32, 64);
        l_run = l_run * al + rs;
#pragma unroll
        for (int ht = 0; ht < 4; ++ht)
#pragma unroll
            for (int r = 0; r < 4; ++r) o[ht][r] *= al;

        // ---- P -> LDS packed (row c, 4 contiguous kv per write) ----
#pragma unroll
        for (int nt = 0; nt < 4; ++nt) {
            u16x4 pk;
#pragma unroll
            for (int r = 0; r < 4; ++r) pk[r] = cvt_bf16(s4[nt][r]);
            *(u16x4*)&Ps[c * 72 + nt * 16 + quad * 4] = pk;
        }
        bf16x8 p0 = ld_bf8(&Ps[c * 72 + quad * 8]);
        bf16x8 p1 = ld_bf8(&Ps[c * 72 + 32 + quad * 8]);

        // ---- O^T += V^T P^T ----
#pragma unroll
        for (int ht = 0; ht < 4; ++ht) {
            o[ht] = MFMA(as_bf8(vc[ht][0]), p0, o[ht]);
            o[ht] = MFMA(as_bf8(vc[ht][1]), p1, o[ht]);
        }

        // rotate K prefetch
#pragma unroll
        for (int nt = 0; nt < 4; ++nt)
#pragma unroll
            for (int kk = 0; kk < 2; ++kk) kc[nt][kk] = kn[nt][kk];
    }

    // ---- store partial: O^T lane c = qrow c; pO [slot][row][h] ----
    unsigned short* po = pO + (size_t)blk * 1024;
#pragma unroll
    for (int ht = 0; ht < 4; ++ht) {
        u16x4 pk;
#pragma unroll
        for (int r = 0; r < 4; ++r) pk[r] = cvt_bf16(o[ht][r]);
        *(u16x4*)(po + c * 64 + ht * 16 + quad * 4) = pk;
    }
    if (quad == 0) {
        pml[(size_t)blk * 32 + c * 2] = m_run;
        pml[(size_t)blk * 32 + c * 2 + 1] = l_run;
    }
}

// ---------------- kernel 4: combine splits -> final output ------------------
// 1024 blocks (b,qt) x 256 thr: rowg = t>>6 (4 rows each), h = t&63.
__global__ __launch_bounds__(256) void combine_kernel(
        const unsigned short* __restrict__ pO, const float* __restrict__ pml,
        float* __restrict__ out) {
    const int blk = blockIdx.x;
    const int b = blk >> 7, qt = blk & 127;
    const int ns = (qt >> 5) + 1;
    const int base = blk * 4;
    const int t = threadIdx.x;
    const int rowg = t >> 6, h = t & 63;

    float msp[4][4], lsp[4][4];
    for (int sp = 0; sp < ns; ++sp)
        for (int r = 0; r < 4; ++r) {
            msp[sp][r] = pml[(size_t)(base + sp) * 32 + (rowg * 4 + r) * 2];
            lsp[sp][r] = pml[(size_t)(base + sp) * 32 + (rowg * 4 + r) * 2 + 1];
        }
    float M[4];
    for (int r = 0; r < 4; ++r) {
        M[r] = msp[0][r];
        for (int sp = 1; sp < ns; ++sp) M[r] = fmaxf(M[r], msp[sp][r]);
    }
    float acc[4] = {}, den[4] = {};
    for (int sp = 0; sp < ns; ++sp)
        for (int r = 0; r < 4; ++r) {
            float wgt = exp2f(msp[sp][r] - M[r]);
            den[r] += lsp[sp][r] * wgt;
            float ov = bf2f(pO[(size_t)(base + sp) * 1024 + (rowg * 4 + r) * 64 + h]);
            acc[r] += ov * wgt;
        }
    for (int r = 0; r < 4; ++r)
        out[(size_t)(b * TT + qt * 16 + rowg * 4 + r) * HS + h] = acc[r] / den[r];
}

extern "C" void kernel_launch(void* const* d_in, const int* in_sizes, int n_in,
                              void* d_out, int out_size, void* d_ws, size_t ws_size,
                              hipStream_t stream) {
    const float* x  = (const float*)d_in[0];
    const int* pm   = (const int*)d_in[1];
    const float* Wq = (const float*)d_in[2];
    const float* Wk = (const float*)d_in[3];
    const float* Wv = (const float*)d_in[4];
    float* out = (float*)d_out;

    unsigned short* wsu  = (unsigned short*)d_ws;
    unsigned short* wbt  = wsu + WBT_E;
    unsigned short* qws  = wsu + Q_E;
    unsigned short* kws  = wsu + K_E;
    unsigned short* vtws = wsu + VT_E;
    unsigned short* pO   = wsu + PO_E;
    float* pml           = (float*)(wsu + PML_E);
    float* biasf         = (float*)(wsu + BIAS_E);

    wconv_kernel<<<48, 256, 0, stream>>>(Wq, Wk, Wv, wbt);
    bias_kernel<<<64, 256, 0, stream>>>(pm, biasf);
    proj_kernel<<<512, 256, 0, stream>>>(x, wbt, qws, kws, vtws);
    flash_kernel<<<4096, 64, 0, stream>>>(qws, kws, vtws, biasf, pO, pml);
    combine_kernel<<<1024, 256, 0, stream>>>(pO, pml, out);
}

// Round 6
// 168.022 us; speedup vs baseline: 1.3162x; 1.3162x over previous
//
#include <hip/hip_runtime.h>

#define DEV static __device__ __forceinline__

typedef float f32x4 __attribute__((ext_vector_type(4)));
typedef __bf16 bf16x8 __attribute__((ext_vector_type(8)));
typedef unsigned short u16x8 __attribute__((ext_vector_type(8)));
typedef unsigned short u16x4 __attribute__((ext_vector_type(4)));

#define MFMA(a, b, c) __builtin_amdgcn_mfma_f32_16x16x32_bf16((a), (b), (c), 0, 0, 0)

// B=8, T=2048, C=1024, H=64
#define TT 2048
#define CE 1024
#define HS 64

// ws layout (ushort elements unless noted)
#define WBT_E 0                   // [3][64 n][1024 k] bf16 (Wq scaled by log2e/32)
#define Q_E   196608              // [B*T][64] bf16
#define K_E   (Q_E + 1048576)
#define VT_E  (K_E + 1048576)     // [B][64 h][2048 t] bf16
#define PO_E  (VT_E + 1048576)    // [512 slots][64 row][64 h] bf16 partial O
#define PML_E (PO_E + 2097152)    // float [512][64 row][2] {m,l}
#define BIAS_E (PML_E + 131072)   // float [B*T] pad bias (0 or -1e30)

DEV unsigned short cvt_bf16(float f) {
    unsigned int u = __builtin_bit_cast(unsigned int, f);
    u += 0x7FFFu + ((u >> 16) & 1u);   // RNE (finite inputs)
    return (unsigned short)(u >> 16);
}

DEV float bf2f(unsigned short v) {
    unsigned int u = ((unsigned int)v) << 16;
    return __builtin_bit_cast(float, u);
}

DEV bf16x8 ld_bf8(const unsigned short* p) {
    union { u16x8 u; bf16x8 b; } v;
    v.u = *(const u16x8*)p;
    return v.b;
}

DEV bf16x8 as_bf8(u16x8 u) {
    union { u16x8 u; bf16x8 b; } v;
    v.u = u;
    return v.b;
}

// async global->LDS, 16B/lane; LDS dst is WAVE-UNIFORM base (+lane*16 by HW)
DEV void glds16(const void* g, void* l) {
    __builtin_amdgcn_global_load_lds(
        (const __attribute__((address_space(1))) void*)g,
        (__attribute__((address_space(3))) void*)l, 16, 0, 0);
}

// ---------------- kernel 1: W fp32 -> bf16 transposed [n][k] ----------------
__global__ __launch_bounds__(256) void wconv_kernel(
        const float* __restrict__ Wq, const float* __restrict__ Wk,
        const float* __restrict__ Wv, unsigned short* __restrict__ wbt) {
    __shared__ unsigned short Tr[64 * 72];
    const int blk = blockIdx.x;
    const int head = blk >> 4, kt = blk & 15;
    const int k0 = kt * 64;
    const float* W = (head == 0) ? Wq : ((head == 1) ? Wk : Wv);
    const float sc = (head == 0) ? 0.045084220027780106f : 1.0f;  // log2(e)/32
    const int t = threadIdx.x;
    const int rrow = t >> 4, c4 = (t & 15) * 4;
    for (int i = 0; i < 4; ++i) {
        int krow = rrow + i * 16;
        f32x4 f = *(const f32x4*)(W + (size_t)(k0 + krow) * 64 + c4);
        Tr[(c4 + 0) * 72 + krow] = cvt_bf16(f[0] * sc);
        Tr[(c4 + 1) * 72 + krow] = cvt_bf16(f[1] * sc);
        Tr[(c4 + 2) * 72 + krow] = cvt_bf16(f[2] * sc);
        Tr[(c4 + 3) * 72 + krow] = cvt_bf16(f[3] * sc);
    }
    __syncthreads();
    const int n = t >> 2, off = (t & 3) * 16;
    u16x8 a0 = *(const u16x8*)&Tr[n * 72 + off];
    u16x8 a1 = *(const u16x8*)&Tr[n * 72 + off + 8];
    unsigned short* dst = wbt + head * 65536 + n * 1024 + k0 + off;
    *(u16x8*)dst = a0;
    *(u16x8*)(dst + 8) = a1;
}

// ---------------- kernel 1b: pad mask -> additive float bias ----------------
__global__ __launch_bounds__(256) void bias_kernel(
        const int* __restrict__ pm, float* __restrict__ biasf) {
    int i = blockIdx.x * 256 + threadIdx.x;   // < 16384
    biasf[i] = pm[i] ? 0.0f : -1e30f;
}

// ---------------- kernel 2: projection q,k = x@W; v transposed -> vt --------
// 512 blocks x 4 waves; 32 rows, 192 cols (wave: wm=w&1 row-half, wn=w>>1
// col-half of 96). K-step 32, double-buffered, ALL staging via
// global_load_lds (zero staging VGPRs), XOR-swizzled for conflict-free reads.
__global__ __launch_bounds__(256) void proj_kernel(
        const float* __restrict__ x, const unsigned short* __restrict__ wbt,
        unsigned short* __restrict__ qws, unsigned short* __restrict__ kws,
        unsigned short* __restrict__ vtws) {
    __shared__ __align__(16) float Xt[2][1024];            // x tile 32x32 f32
    __shared__ __align__(16) unsigned short Wt[2][6144];   // W tile 192x32 bf16
    __shared__ __align__(16) unsigned short TT2[64 * 48];  // v-transpose scratch

    const int t = threadIdx.x;
    const int lane = t & 63, w = t >> 6;
    const int quad = lane >> 4, c = lane & 15;
    const int wm = w & 1, wn = w >> 1;
    const int t0 = blockIdx.x * 32;

    // staging geometry (see swizzle notes: cb_stored = cb' ^ key(row))
    const int srow = lane >> 3, scb = (lane & 7) ^ srow;   // x: 8x16B rows
    const float* xg = x + (size_t)(t0 + w * 8 + srow) * CE + scb * 4;
    const int wrow_lo = lane >> 2;                         // W: 4x16B rows
    const int wcb = (lane & 3) ^ (wrow_lo & 3);
    const unsigned short* wg0 = wbt + (size_t)((3 * w + 0) * 16 + wrow_lo) * 1024 + wcb * 8;
    const unsigned short* wg1 = wbt + (size_t)((3 * w + 1) * 16 + wrow_lo) * 1024 + wcb * 8;
    const unsigned short* wg2 = wbt + (size_t)((3 * w + 2) * 16 + wrow_lo) * 1024 + wcb * 8;

    f32x4 acc[6] = {};

    // prologue: stage step 0 into buffer 0
    glds16(xg, &Xt[0][w * 256]);
    glds16(wg0, &Wt[0][(3 * w + 0) * 512]);
    glds16(wg1, &Wt[0][(3 * w + 1) * 512]);
    glds16(wg2, &Wt[0][(3 * w + 2) * 512]);
    __syncthreads();

    const int r = wm * 16 + c;           // A-frag row
    const int ck7 = c & 7, ck3 = c & 3;  // swizzle keys

    for (int step = 0; step < 32; ++step) {
        const int pb = step & 1, nb = pb ^ 1;
        const int ksn = ((step + 1) & 31) * 32;   // wraps on last (discarded)
        // ---- async-stage step+1 ----
        glds16(xg + ksn, &Xt[nb][w * 256]);
        glds16(wg0 + ksn, &Wt[nb][(3 * w + 0) * 512]);
        glds16(wg1 + ksn, &Wt[nb][(3 * w + 1) * 512]);
        glds16(wg2 + ksn, &Wt[nb][(3 * w + 2) * 512]);
        // ---- compute current ----
        f32x4 v0 = *(const f32x4*)&Xt[pb][r * 32 + (((2 * quad) ^ ck7) * 4)];
        f32x4 v1 = *(const f32x4*)&Xt[pb][r * 32 + (((2 * quad + 1) ^ ck7) * 4)];
        u16x8 ap;
#pragma unroll
        for (int j = 0; j < 4; ++j) { ap[j] = cvt_bf16(v0[j]); ap[4 + j] = cvt_bf16(v1[j]); }
        bf16x8 af = as_bf8(ap);
#pragma unroll
        for (int nt = 0; nt < 6; ++nt) {
            int n = wn * 96 + nt * 16 + c;
            bf16x8 bb = ld_bf8(&Wt[pb][n * 32 + ((quad ^ ck3) * 8)]);
            acc[nt] = MFMA(af, bb, acc[nt]);
        }
        __syncthreads();
    }

    // epilogue: q,k direct; v transposed via LDS (64 h x 32 t, stride 48)
    for (int nt = 0; nt < 6; ++nt) {
        int col = wn * 96 + nt * 16 + c;
        f32x4 a = acc[nt];
        for (int r4 = 0; r4 < 4; ++r4) {
            int row = wm * 16 + quad * 4 + r4;
            size_t tg = (size_t)(t0 + row);
            unsigned short hv = cvt_bf16(a[r4]);
            if (col < 64)       qws[tg * HS + col] = hv;
            else if (col < 128) kws[tg * HS + col - 64] = hv;
            else                TT2[(col - 128) * 48 + row] = hv;
        }
    }
    __syncthreads();
    {
        int h = t >> 2, off = (t & 3) * 8;
        u16x8 v = *(const u16x8*)&TT2[h * 48 + off];
        int b = t0 >> 11, tl0 = t0 & 2047;
        *(u16x8*)(vtws + (size_t)(b * 64 + h) * TT + tl0 + off) = v;
    }
}

// ---------------- kernel 3: flash, 4-wave blocks, glds-staged K/V -----------
// 512 blocks: sp=blk>>8; r8=blk&255; b=r8&7; qt=r8>>3 (sp1: 31-qt for balance).
// Block = 64 q-rows (wave w: rows qt*64+w*16+{c}), kv-iters of 64, split x2.
// S^T = K·Q^T per wave (lane c owns q-row -> scalar softmax state).
// K/V staged once per block via global_load_lds (XOR-swizzled), dbuf,
// ONE barrier/iter. Partials (unnorm O bf16, m/l) -> combine pass.
__global__ __launch_bounds__(256) void flash_kernel(
        const unsigned short* __restrict__ qws, const unsigned short* __restrict__ kws,
        const unsigned short* __restrict__ vtws, const float* __restrict__ biasf,
        unsigned short* __restrict__ pO, float* __restrict__ pml) {
    __shared__ __align__(16) unsigned short Kt[2][4096];  // [kv 64][h 64] swizzled
    __shared__ __align__(16) unsigned short Vt[2][4096];  // [h 64][kv 64] swizzled
    __shared__ __align__(16) unsigned short Ps[4][1152];  // per-wave P [q16][kv 64+8]

    const int t = threadIdx.x, blk = blockIdx.x;
    const int sp = blk >> 8, r8 = blk & 255, b = r8 & 7;
    int qt = r8 >> 3;
    if (sp) qt = 31 - qt;
    if (sp && qt == 0) return;               // empty second split
    const int half = (qt + 2) >> 1;
    const int jbeg = sp ? half : 0;
    const int jend = sp ? qt + 1 : half;

    const int lane = t & 63, w = t >> 6;
    const int quad = lane >> 4, c = lane & 15;

    // staging geometry: instrs i0=2w, i1=2w+1 of 8; row = i*8 + (lane>>3)
    const int srow = lane >> 3, scb = (lane & 7) ^ srow;
    const unsigned short* kg0 = kws + (size_t)(b * TT + 2 * w * 8 + srow) * HS + scb * 8;
    const unsigned short* kg1 = kg0 + (size_t)8 * HS;
    const unsigned short* vg0 = vtws + (size_t)(b * 64 + 2 * w * 8 + srow) * TT + scb * 8;
    const unsigned short* vg1 = vg0 + (size_t)8 * TT;

    // Q B-frag (n = qrow = c)
    bf16x8 qf[2];
#pragma unroll
    for (int kk = 0; kk < 2; ++kk)
        qf[kk] = ld_bf8(qws + (size_t)(b * TT + qt * 64 + w * 16 + c) * HS + kk * 32 + quad * 8);

    const float* bbase = biasf + b * TT + quad * 4;
    const int ck7 = c & 7;

    // prologue: stage iter jbeg -> buffer 0
    {
        int kv = jbeg * 64;
        glds16(kg0 + (size_t)kv * HS, &Kt[0][(2 * w + 0) * 512]);
        glds16(kg1 + (size_t)kv * HS, &Kt[0][(2 * w + 1) * 512]);
        glds16(vg0 + kv, &Vt[0][(2 * w + 0) * 512]);
        glds16(vg1 + kv, &Vt[0][(2 * w + 1) * 512]);
    }
    __syncthreads();

    f32x4 o[4] = {};
    float m_run = -1e30f, l_run = 0.0f;

    for (int j = jbeg; j < jend; ++j) {
        const int pb = (j - jbeg) & 1, nb = pb ^ 1;
        const int jn = (j + 1 < jend) ? j + 1 : j;   // last: dummy restage
        // ---- async-stage next iter ----
        {
            int kv = jn * 64;
            glds16(kg0 + (size_t)kv * HS, &Kt[nb][(2 * w + 0) * 512]);
            glds16(kg1 + (size_t)kv * HS, &Kt[nb][(2 * w + 1) * 512]);
            glds16(vg0 + kv, &Vt[nb][(2 * w + 0) * 512]);
            glds16(vg1 + kv, &Vt[nb][(2 * w + 1) * 512]);
        }
        // ---- bias ----
        f32x4 bv[4];
#pragma unroll
        for (int nt = 0; nt < 4; ++nt)
            bv[nt] = *(const f32x4*)(bbase + j * 64 + nt * 16);

        // ---- S^T = K Q^T ----
        f32x4 s4[4] = {};
#pragma unroll
        for (int kk = 0; kk < 2; ++kk)
#pragma unroll
            for (int nt = 0; nt < 4; ++nt) {
                bf16x8 ka = ld_bf8(&Kt[pb][(nt * 16 + c) * 64 + (((kk * 4 + quad) ^ ck7) * 8)]);
                s4[nt] = MFMA(ka, qf[kk], s4[nt]);
            }

        // ---- mask (causal only on diagonal iter) + bias ----
        if (j == qt) {
            const int qrl = w * 16 + c;
#pragma unroll
            for (int nt = 0; nt < 4; ++nt)
#pragma unroll
                for (int r = 0; r < 4; ++r) {
                    int kvl = nt * 16 + quad * 4 + r;
                    s4[nt][r] = (kvl > qrl) ? -1e30f : (s4[nt][r] + bv[nt][r]);
                }
        } else {
#pragma unroll
            for (int nt = 0; nt < 4; ++nt)
#pragma unroll
                for (int r = 0; r < 4; ++r) s4[nt][r] += bv[nt][r];
        }

        // ---- online softmax: in-lane tree + 2 shfls, scalar state ----
        float mx = s4[0][0];
#pragma unroll
        for (int nt = 0; nt < 4; ++nt)
#pragma unroll
            for (int r = 0; r < 4; ++r) mx = fmaxf(mx, s4[nt][r]);
        mx = fmaxf(mx, __shfl_xor(mx, 16, 64));
        mx = fmaxf(mx, __shfl_xor(mx, 32, 64));
        float mnew = fmaxf(m_run, mx);
        float al = exp2f(m_run - mnew);
        m_run = mnew;
#pragma unroll
        for (int nt = 0; nt < 4; ++nt)
#pragma unroll
            for (int r = 0; r < 4; ++r) s4[nt][r] = exp2f(s4[nt][r] - mnew);
        float rs = 0.0f;
#pragma unroll
        for (int nt = 0; nt < 4; ++nt)
            rs += (s4[nt][0] + s4[nt][1]) + (s4[nt][2] + s4[nt][3]);
        rs += __shfl_xor(rs, 16, 64);
        rs += __shfl_xor(rs, 32, 64);
        l_run = l_run * al + rs;
#pragma unroll
        for (int ht = 0; ht < 4; ++ht)
#pragma unroll
            for (int r = 0; r < 4; ++r) o[ht][r] *= al;

        // ---- P -> wave-private LDS, repack to B-frag ----
#pragma unroll
        for (int nt = 0; nt < 4; ++nt) {
            u16x4 pk;
#pragma unroll
            for (int r = 0; r < 4; ++r) pk[r] = cvt_bf16(s4[nt][r]);
            *(u16x4*)&Ps[w][c * 72 + nt * 16 + quad * 4] = pk;
        }
        bf16x8 p0 = ld_bf8(&Ps[w][c * 72 + quad * 8]);
        bf16x8 p1 = ld_bf8(&Ps[w][c * 72 + 32 + quad * 8]);

        // ---- O^T += V^T P^T ----
#pragma unroll
        for (int kk = 0; kk < 2; ++kk) {
            bf16x8 pa = kk ? p1 : p0;
#pragma unroll
            for (int ht = 0; ht < 4; ++ht) {
                bf16x8 va = ld_bf8(&Vt[pb][(ht * 16 + c) * 64 + (((kk * 4 + quad) ^ ck7) * 8)]);
                o[ht] = MFMA(va, pa, o[ht]);
            }
        }
        __syncthreads();
    }

    // ---- store partials: slot = blk; pO [slot][row 64][h 64] ----
    unsigned short* po = pO + (size_t)blk * 4096;
#pragma unroll
    for (int ht = 0; ht < 4; ++ht) {
        u16x4 pk;
#pragma unroll
        for (int r = 0; r < 4; ++r) pk[r] = cvt_bf16(o[ht][r]);
        *(u16x4*)(po + (w * 16 + c) * 64 + ht * 16 + quad * 4) = pk;
    }
    if (quad == 0) {
        pml[(size_t)blk * 128 + (w * 16 + c) * 2] = m_run;
        pml[(size_t)blk * 128 + (w * 16 + c) * 2 + 1] = l_run;
    }
}

// ---------------- kernel 4: combine 2 splits -> final output ----------------
// 256 blocks (b,qt) x 256 thr; slot0 = qt*8+b, slot1 = 256 + (31-qt)*8 + b.
__global__ __launch_bounds__(256) void combine_kernel(
        const unsigned short* __restrict__ pO, const float* __restrict__ pml,
        float* __restrict__ out) {
    const int blk = blockIdx.x;
    const int qt = blk >> 3, b = blk & 7;
    const int s0 = qt * 8 + b, s1 = 256 + (31 - qt) * 8 + b;
    const bool two = (qt > 0);
    const int t = threadIdx.x, h = t & 63, rg = t >> 6;
    for (int i = 0; i < 16; ++i) {
        int row = rg + i * 4;
        float m0 = pml[(size_t)s0 * 128 + row * 2];
        float l0 = pml[(size_t)s0 * 128 + row * 2 + 1];
        float o0 = bf2f(pO[(size_t)s0 * 4096 + row * 64 + h]);
        float num, den;
        if (two) {
            float m1 = pml[(size_t)s1 * 128 + row * 2];
            float l1 = pml[(size_t)s1 * 128 + row * 2 + 1];
            float o1 = bf2f(pO[(size_t)s1 * 4096 + row * 64 + h]);
            float M = fmaxf(m0, m1);
            float w0 = exp2f(m0 - M), w1 = exp2f(m1 - M);
            num = o0 * w0 + o1 * w1;
            den = l0 * w0 + l1 * w1;
        } else {
            num = o0; den = l0;
        }
        out[(size_t)(b * TT + qt * 64 + row) * HS + h] = num / den;
    }
}

extern "C" void kernel_launch(void* const* d_in, const int* in_sizes, int n_in,
                              void* d_out, int out_size, void* d_ws, size_t ws_size,
                              hipStream_t stream) {
    const float* x  = (const float*)d_in[0];
    const int* pm   = (const int*)d_in[1];
    const float* Wq = (const float*)d_in[2];
    const float* Wk = (const float*)d_in[3];
    const float* Wv = (const float*)d_in[4];
    float* out = (float*)d_out;

    unsigned short* wsu  = (unsigned short*)d_ws;
    unsigned short* wbt  = wsu + WBT_E;
    unsigned short* qws  = wsu + Q_E;
    unsigned short* kws  = wsu + K_E;
    unsigned short* vtws = wsu + VT_E;
    unsigned short* pO   = wsu + PO_E;
    float* pml           = (float*)(wsu + PML_E);
    float* biasf         = (float*)(wsu + BIAS_E);

    wconv_kernel<<<48, 256, 0, stream>>>(Wq, Wk, Wv, wbt);
    bias_kernel<<<64, 256, 0, stream>>>(pm, biasf);
    proj_kernel<<<512, 256, 0, stream>>>(x, wbt, qws, kws, vtws);
    flash_kernel<<<512, 256, 0, stream>>>(qws, kws, vtws, biasf, pO, pml);
    combine_kernel<<<256, 256, 0, stream>>>(pO, pml, out);
}

// Round 7
// 159.120 us; speedup vs baseline: 1.3899x; 1.0559x over previous
//
#include <hip/hip_runtime.h>

#define DEV static __device__ __forceinline__

typedef float f32x4 __attribute__((ext_vector_type(4)));
typedef __bf16 bf16x8 __attribute__((ext_vector_type(8)));
typedef unsigned short u16x8 __attribute__((ext_vector_type(8)));
typedef unsigned short u16x4 __attribute__((ext_vector_type(4)));

#define MFMA(a, b, c) __builtin_amdgcn_mfma_f32_16x16x32_bf16((a), (b), (c), 0, 0, 0)

// fine-grained barrier: wait only the 4 OLDEST outstanding glds (the buffer
// about to be read, issued 2 iters ago), never vmcnt(0). AITER pattern.
#define WAIT4_BARRIER() asm volatile("s_waitcnt vmcnt(4)\n\ts_barrier" ::: "memory")

// B=8, T=2048, C=1024, H=64
#define TT 2048
#define CE 1024
#define HS 64

// ws layout (ushort elements unless noted)
#define WBT_E 0                   // [3][64 n][1024 k] bf16 (Wq scaled by log2e/32)
#define Q_E   196608              // [B*T][64] bf16
#define K_E   (Q_E + 1048576)
#define VT_E  (K_E + 1048576)     // [B][64 h][2048 t] bf16
#define PO_E  (VT_E + 1048576)    // [512 slots][64 row][64 h] bf16 partial O
#define PML_E (PO_E + 2097152)    // float [512][64 row][2] {m,l}
#define BIAS_E (PML_E + 131072)   // float [B*T] pad bias (0 or -1e30)

DEV unsigned short cvt_bf16(float f) {
    unsigned int u = __builtin_bit_cast(unsigned int, f);
    u += 0x7FFFu + ((u >> 16) & 1u);   // RNE (finite inputs)
    return (unsigned short)(u >> 16);
}

DEV float bf2f(unsigned short v) {
    unsigned int u = ((unsigned int)v) << 16;
    return __builtin_bit_cast(float, u);
}

DEV bf16x8 ld_bf8(const unsigned short* p) {
    union { u16x8 u; bf16x8 b; } v;
    v.u = *(const u16x8*)p;
    return v.b;
}

DEV bf16x8 as_bf8(u16x8 u) {
    union { u16x8 u; bf16x8 b; } v;
    v.u = u;
    return v.b;
}

// async global->LDS, 16B/lane; LDS dst is WAVE-UNIFORM base (+lane*16 by HW)
DEV void glds16(const void* g, void* l) {
    __builtin_amdgcn_global_load_lds(
        (const __attribute__((address_space(1))) void*)g,
        (__attribute__((address_space(3))) void*)l, 16, 0, 0);
}

// ---------------- kernel 1: W fp32 -> bf16 transposed [n][k] ----------------
__global__ __launch_bounds__(256) void wconv_kernel(
        const float* __restrict__ Wq, const float* __restrict__ Wk,
        const float* __restrict__ Wv, unsigned short* __restrict__ wbt) {
    __shared__ unsigned short Tr[64 * 72];
    const int blk = blockIdx.x;
    const int head = blk >> 4, kt = blk & 15;
    const int k0 = kt * 64;
    const float* W = (head == 0) ? Wq : ((head == 1) ? Wk : Wv);
    const float sc = (head == 0) ? 0.045084220027780106f : 1.0f;  // log2(e)/32
    const int t = threadIdx.x;
    const int rrow = t >> 4, c4 = (t & 15) * 4;
    for (int i = 0; i < 4; ++i) {
        int krow = rrow + i * 16;
        f32x4 f = *(const f32x4*)(W + (size_t)(k0 + krow) * 64 + c4);
        Tr[(c4 + 0) * 72 + krow] = cvt_bf16(f[0] * sc);
        Tr[(c4 + 1) * 72 + krow] = cvt_bf16(f[1] * sc);
        Tr[(c4 + 2) * 72 + krow] = cvt_bf16(f[2] * sc);
        Tr[(c4 + 3) * 72 + krow] = cvt_bf16(f[3] * sc);
    }
    __syncthreads();
    const int n = t >> 2, off = (t & 3) * 16;
    u16x8 a0 = *(const u16x8*)&Tr[n * 72 + off];
    u16x8 a1 = *(const u16x8*)&Tr[n * 72 + off + 8];
    unsigned short* dst = wbt + head * 65536 + n * 1024 + k0 + off;
    *(u16x8*)dst = a0;
    *(u16x8*)(dst + 8) = a1;
}

// ---------------- kernel 1b: pad mask -> additive float bias ----------------
__global__ __launch_bounds__(256) void bias_kernel(
        const int* __restrict__ pm, float* __restrict__ biasf) {
    int i = blockIdx.x * 256 + threadIdx.x;   // < 16384
    biasf[i] = pm[i] ? 0.0f : -1e30f;
}

// ---------------- kernel 2: projection q,k = x@W; v transposed -> vt --------
// 512 blocks x 4 waves; 32 rows, 192 cols. K-step 32, TRIPLE-buffered glds
// staging issued 2 steps ahead; barrier = s_waitcnt vmcnt(4) + s_barrier
// (in-loop VMEM is exactly the 4 glds/wave, so the count is exact).
__global__ __launch_bounds__(256) void proj_kernel(
        const float* __restrict__ x, const unsigned short* __restrict__ wbt,
        unsigned short* __restrict__ qws, unsigned short* __restrict__ kws,
        unsigned short* __restrict__ vtws) {
    __shared__ __align__(16) float Xt[3][1024];            // x tile 32x32 f32
    __shared__ __align__(16) unsigned short Wt[3][6144];   // W tile 192x32 bf16
    __shared__ __align__(16) unsigned short TT2[64 * 48];  // v-transpose scratch

    const int t = threadIdx.x;
    const int lane = t & 63, w = t >> 6;
    const int quad = lane >> 4, c = lane & 15;
    const int wm = w & 1, wn = w >> 1;
    const int t0 = blockIdx.x * 32;

    // staging geometry (XOR swizzle: cb_stored = cb' ^ key(row))
    const int srow = lane >> 3, scb = (lane & 7) ^ srow;   // x: 8x16B rows
    const float* xg = x + (size_t)(t0 + w * 8 + srow) * CE + scb * 4;
    const int wrow_lo = lane >> 2;                         // W: 4x16B rows
    const int wcb = (lane & 3) ^ (wrow_lo & 3);
    const unsigned short* wg0 = wbt + (size_t)((3 * w + 0) * 16 + wrow_lo) * 1024 + wcb * 8;
    const unsigned short* wg1 = wbt + (size_t)((3 * w + 1) * 16 + wrow_lo) * 1024 + wcb * 8;
    const unsigned short* wg2 = wbt + (size_t)((3 * w + 2) * 16 + wrow_lo) * 1024 + wcb * 8;

    f32x4 acc[6] = {};

    // prologue: stage steps 0,1 into buffers 0,1 (8 glds in flight)
#pragma unroll
    for (int s = 0; s < 2; ++s) {
        const int ks = s * 32;
        glds16(xg + ks, &Xt[s][w * 256]);
        glds16(wg0 + ks, &Wt[s][(3 * w + 0) * 512]);
        glds16(wg1 + ks, &Wt[s][(3 * w + 1) * 512]);
        glds16(wg2 + ks, &Wt[s][(3 * w + 2) * 512]);
    }

    const int r = wm * 16 + c;           // A-frag row
    const int ck7 = c & 7, ck3 = c & 3;  // swizzle keys

    int pb = 0, nb = 2;
    for (int step = 0; step < 32; ++step) {
        WAIT4_BARRIER();                 // oldest 4 glds (buffer pb) landed
        // ---- compute current buffer ----
        f32x4 v0 = *(const f32x4*)&Xt[pb][r * 32 + (((2 * quad) ^ ck7) * 4)];
        f32x4 v1 = *(const f32x4*)&Xt[pb][r * 32 + (((2 * quad + 1) ^ ck7) * 4)];
        u16x8 ap;
#pragma unroll
        for (int j = 0; j < 4; ++j) { ap[j] = cvt_bf16(v0[j]); ap[4 + j] = cvt_bf16(v1[j]); }
        bf16x8 af = as_bf8(ap);
#pragma unroll
        for (int nt = 0; nt < 6; ++nt) {
            int n = wn * 96 + nt * 16 + c;
            bf16x8 bb = ld_bf8(&Wt[pb][n * 32 + ((quad ^ ck3) * 8)]);
            acc[nt] = MFMA(af, bb, acc[nt]);
        }
        // ---- issue step+2 into buffer nb (safe: all waves crossed this
        // iter's barrier => finished reading nb in iter step-1) ----
        const int ksn = ((step + 2) & 31) * 32;   // wraps at end (discarded)
        glds16(xg + ksn, &Xt[nb][w * 256]);
        glds16(wg0 + ksn, &Wt[nb][(3 * w + 0) * 512]);
        glds16(wg1 + ksn, &Wt[nb][(3 * w + 1) * 512]);
        glds16(wg2 + ksn, &Wt[nb][(3 * w + 2) * 512]);
        pb = (pb == 2) ? 0 : pb + 1;
        nb = (nb == 2) ? 0 : nb + 1;
    }

    // epilogue: q,k direct; v transposed via LDS (64 h x 32 t, stride 48)
    for (int nt = 0; nt < 6; ++nt) {
        int col = wn * 96 + nt * 16 + c;
        f32x4 a = acc[nt];
        for (int r4 = 0; r4 < 4; ++r4) {
            int row = wm * 16 + quad * 4 + r4;
            size_t tg = (size_t)(t0 + row);
            unsigned short hv = cvt_bf16(a[r4]);
            if (col < 64)       qws[tg * HS + col] = hv;
            else if (col < 128) kws[tg * HS + col - 64] = hv;
            else                TT2[(col - 128) * 48 + row] = hv;
        }
    }
    __syncthreads();
    {
        int h = t >> 2, off = (t & 3) * 8;
        u16x8 v = *(const u16x8*)&TT2[h * 48 + off];
        int b = t0 >> 11, tl0 = t0 & 2047;
        *(u16x8*)(vtws + (size_t)(b * 64 + h) * TT + tl0 + off) = v;
    }
}

// ---------------- kernel 3: flash, triple-buffered glds, fine vmcnt ---------
// 512 blocks: sp=blk>>8; r8=blk&255; b=r8&7; qt=r8>>3 (sp1: 31-qt balance).
// Block = 64 q-rows; S^T = K.Q^T per wave (lane c owns q-row -> scalar
// softmax state). Bias staged to LDS in prologue so in-loop VMEM is exactly
// the 4 glds/wave. One fine-grained barrier per iter, glds 2 iters ahead.
__global__ __launch_bounds__(256) void flash_kernel(
        const unsigned short* __restrict__ qws, const unsigned short* __restrict__ kws,
        const unsigned short* __restrict__ vtws, const float* __restrict__ biasf,
        unsigned short* __restrict__ pO, float* __restrict__ pml) {
    __shared__ __align__(16) unsigned short Kt[3][4096];  // [kv 64][h 64] swizzled
    __shared__ __align__(16) unsigned short Vt[3][4096];  // [h 64][kv 64] swizzled
    __shared__ __align__(16) unsigned short Ps[4][1152];  // per-wave P [q16][kv 64+8]
    __shared__ __align__(16) float Bs[1024];              // bias for <=16 iters

    const int t = threadIdx.x, blk = blockIdx.x;
    const int sp = blk >> 8, r8 = blk & 255, b = r8 & 7;
    int qt = r8 >> 3;
    if (sp) qt = 31 - qt;
    if (sp && qt == 0) return;               // empty second split
    const int half = (qt + 2) >> 1;
    const int jbeg = sp ? half : 0;
    const int jend = sp ? qt + 1 : half;
    const int niter = jend - jbeg;           // <= 16

    const int lane = t & 63, w = t >> 6;
    const int quad = lane >> 4, c = lane & 15;

    // staging geometry: instrs i0=2w, i1=2w+1 of 8; row = i*8 + (lane>>3)
    const int srow = lane >> 3, scb = (lane & 7) ^ srow;
    const unsigned short* kg0 = kws + (size_t)(b * TT + 2 * w * 8 + srow) * HS + scb * 8;
    const unsigned short* kg1 = kg0 + (size_t)8 * HS;
    const unsigned short* vg0 = vtws + (size_t)(b * 64 + 2 * w * 8 + srow) * TT + scb * 8;
    const unsigned short* vg1 = vg0 + (size_t)8 * TT;

    // Q B-frag (n = qrow = c)
    bf16x8 qf[2];
#pragma unroll
    for (int kk = 0; kk < 2; ++kk)
        qf[kk] = ld_bf8(qws + (size_t)(b * TT + qt * 64 + w * 16 + c) * HS + kk * 32 + quad * 8);

    // stage bias to LDS (keeps in-loop vmcnt exact)
    {
        int bi = t * 4;
        if (bi < niter * 64)
            *(f32x4*)&Bs[bi] = *(const f32x4*)(biasf + b * TT + jbeg * 64 + bi);
    }

    // prologue: stage iters jbeg, jbeg+1 (clamped) into buffers 0,1
#pragma unroll
    for (int s = 0; s < 2; ++s) {
        int jj = jbeg + s; if (jj > jend - 1) jj = jend - 1;
        const int kv = jj * 64;
        glds16(kg0 + (size_t)kv * HS, &Kt[s][(2 * w + 0) * 512]);
        glds16(kg1 + (size_t)kv * HS, &Kt[s][(2 * w + 1) * 512]);
        glds16(vg0 + kv, &Vt[s][(2 * w + 0) * 512]);
        glds16(vg1 + kv, &Vt[s][(2 * w + 1) * 512]);
    }
    __syncthreads();   // one-time full drain: bias LDS + prologue glds

    f32x4 o[4] = {};
    float m_run = -1e30f, l_run = 0.0f;
    const int ck7 = c & 7;

    int pb = 0, nb = 2;
    for (int j = jbeg; j < jend; ++j) {
        WAIT4_BARRIER();                 // buffer pb's 4 glds landed
        // ---- bias from LDS ----
        f32x4 bv[4];
#pragma unroll
        for (int nt = 0; nt < 4; ++nt)
            bv[nt] = *(const f32x4*)&Bs[(j - jbeg) * 64 + nt * 16 + quad * 4];

        // ---- S^T = K Q^T ----
        f32x4 s4[4] = {};
#pragma unroll
        for (int kk = 0; kk < 2; ++kk)
#pragma unroll
            for (int nt = 0; nt < 4; ++nt) {
                bf16x8 ka = ld_bf8(&Kt[pb][(nt * 16 + c) * 64 + (((kk * 4 + quad) ^ ck7) * 8)]);
                s4[nt] = MFMA(ka, qf[kk], s4[nt]);
            }

        // ---- mask (causal only on diagonal iter) + bias ----
        if (j == qt) {
            const int qrl = w * 16 + c;
#pragma unroll
            for (int nt = 0; nt < 4; ++nt)
#pragma unroll
                for (int r = 0; r < 4; ++r) {
                    int kvl = nt * 16 + quad * 4 + r;
                    s4[nt][r] = (kvl > qrl) ? -1e30f : (s4[nt][r] + bv[nt][r]);
                }
        } else {
#pragma unroll
            for (int nt = 0; nt < 4; ++nt)
#pragma unroll
                for (int r = 0; r < 4; ++r) s4[nt][r] += bv[nt][r];
        }

        // ---- online softmax: in-lane tree + 2 shfls, scalar state ----
        float mx = s4[0][0];
#pragma unroll
        for (int nt = 0; nt < 4; ++nt)
#pragma unroll
            for (int r = 0; r < 4; ++r) mx = fmaxf(mx, s4[nt][r]);
        mx = fmaxf(mx, __shfl_xor(mx, 16, 64));
        mx = fmaxf(mx, __shfl_xor(mx, 32, 64));
        float mnew = fmaxf(m_run, mx);
        float al = exp2f(m_run - mnew);
        m_run = mnew;
#pragma unroll
        for (int nt = 0; nt < 4; ++nt)
#pragma unroll
            for (int r = 0; r < 4; ++r) s4[nt][r] = exp2f(s4[nt][r] - mnew);
        float rs = 0.0f;
#pragma unroll
        for (int nt = 0; nt < 4; ++nt)
            rs += (s4[nt][0] + s4[nt][1]) + (s4[nt][2] + s4[nt][3]);
        rs += __shfl_xor(rs, 16, 64);
        rs += __shfl_xor(rs, 32, 64);
        l_run = l_run * al + rs;
#pragma unroll
        for (int ht = 0; ht < 4; ++ht)
#pragma unroll
            for (int r = 0; r < 4; ++r) o[ht][r] *= al;

        // ---- P -> wave-private LDS, repack to B-frag ----
#pragma unroll
        for (int nt = 0; nt < 4; ++nt) {
            u16x4 pk;
#pragma unroll
            for (int r = 0; r < 4; ++r) pk[r] = cvt_bf16(s4[nt][r]);
            *(u16x4*)&Ps[w][c * 72 + nt * 16 + quad * 4] = pk;
        }
        bf16x8 p0 = ld_bf8(&Ps[w][c * 72 + quad * 8]);
        bf16x8 p1 = ld_bf8(&Ps[w][c * 72 + 32 + quad * 8]);

        // ---- O^T += V^T P^T ----
#pragma unroll
        for (int kk = 0; kk < 2; ++kk) {
            bf16x8 pa = kk ? p1 : p0;
#pragma unroll
            for (int ht = 0; ht < 4; ++ht) {
                bf16x8 va = ld_bf8(&Vt[pb][(ht * 16 + c) * 64 + (((kk * 4 + quad) ^ ck7) * 8)]);
                o[ht] = MFMA(va, pa, o[ht]);
            }
        }

        // ---- issue iter j+2 into buffer nb (write-after-read safe) ----
        {
            int jn = j + 2; if (jn > jend - 1) jn = jend - 1;
            const int kv = jn * 64;
            glds16(kg0 + (size_t)kv * HS, &Kt[nb][(2 * w + 0) * 512]);
            glds16(kg1 + (size_t)kv * HS, &Kt[nb][(2 * w + 1) * 512]);
            glds16(vg0 + kv, &Vt[nb][(2 * w + 0) * 512]);
            glds16(vg1 + kv, &Vt[nb][(2 * w + 1) * 512]);
        }
        pb = (pb == 2) ? 0 : pb + 1;
        nb = (nb == 2) ? 0 : nb + 1;
    }

    // ---- store partials: slot = blk; pO [slot][row 64][h 64] ----
    unsigned short* po = pO + (size_t)blk * 4096;
#pragma unroll
    for (int ht = 0; ht < 4; ++ht) {
        u16x4 pk;
#pragma unroll
        for (int r = 0; r < 4; ++r) pk[r] = cvt_bf16(o[ht][r]);
        *(u16x4*)(po + (w * 16 + c) * 64 + ht * 16 + quad * 4) = pk;
    }
    if (quad == 0) {
        pml[(size_t)blk * 128 + (w * 16 + c) * 2] = m_run;
        pml[(size_t)blk * 128 + (w * 16 + c) * 2 + 1] = l_run;
    }
}

// ---------------- kernel 4: combine 2 splits -> final output ----------------
// 256 blocks (b,qt) x 256 thr; slot0 = qt*8+b, slot1 = 256 + (31-qt)*8 + b.
__global__ __launch_bounds__(256) void combine_kernel(
        const unsigned short* __restrict__ pO, const float* __restrict__ pml,
        float* __restrict__ out) {
    const int blk = blockIdx.x;
    const int qt = blk >> 3, b = blk & 7;
    const int s0 = qt * 8 + b, s1 = 256 + (31 - qt) * 8 + b;
    const bool two = (qt > 0);
    const int t = threadIdx.x, h = t & 63, rg = t >> 6;
    for (int i = 0; i < 16; ++i) {
        int row = rg + i * 4;
        float m0 = pml[(size_t)s0 * 128 + row * 2];
        float l0 = pml[(size_t)s0 * 128 + row * 2 + 1];
        float o0 = bf2f(pO[(size_t)s0 * 4096 + row * 64 + h]);
        float num, den;
        if (two) {
            float m1 = pml[(size_t)s1 * 128 + row * 2];
            float l1 = pml[(size_t)s1 * 128 + row * 2 + 1];
            float o1 = bf2f(pO[(size_t)s1 * 4096 + row * 64 + h]);
            float M = fmaxf(m0, m1);
            float w0 = exp2f(m0 - M), w1 = exp2f(m1 - M);
            num = o0 * w0 + o1 * w1;
            den = l0 * w0 + l1 * w1;
        } else {
            num = o0; den = l0;
        }
        out[(size_t)(b * TT + qt * 64 + row) * HS + h] = num / den;
    }
}

extern "C" void kernel_launch(void* const* d_in, const int* in_sizes, int n_in,
                              void* d_out, int out_size, void* d_ws, size_t ws_size,
                              hipStream_t stream) {
    const float* x  = (const float*)d_in[0];
    const int* pm   = (const int*)d_in[1];
    const float* Wq = (const float*)d_in[2];
    const float* Wk = (const float*)d_in[3];
    const float* Wv = (const float*)d_in[4];
    float* out = (float*)d_out;

    unsigned short* wsu  = (unsigned short*)d_ws;
    unsigned short* wbt  = wsu + WBT_E;
    unsigned short* qws  = wsu + Q_E;
    unsigned short* kws  = wsu + K_E;
    unsigned short* vtws = wsu + VT_E;
    unsigned short* pO   = wsu + PO_E;
    float* pml           = (float*)(wsu + PML_E);
    float* biasf         = (float*)(wsu + BIAS_E);

    wconv_kernel<<<48, 256, 0, stream>>>(Wq, Wk, Wv, wbt);
    bias_kernel<<<64, 256, 0, stream>>>(pm, biasf);
    proj_kernel<<<512, 256, 0, stream>>>(x, wbt, qws, kws, vtws);
    flash_kernel<<<512, 256, 0, stream>>>(qws, kws, vtws, biasf, pO, pml);
    combine_kernel<<<256, 256, 0, stream>>>(pO, pml, out);
}

// Round 8
// 158.352 us; speedup vs baseline: 1.3966x; 1.0049x over previous
//
#include <hip/hip_runtime.h>

#define DEV static __device__ __forceinline__

typedef float f32x4 __attribute__((ext_vector_type(4)));
typedef int i32x4 __attribute__((ext_vector_type(4)));
typedef __bf16 bf16x8 __attribute__((ext_vector_type(8)));
typedef unsigned short u16x8 __attribute__((ext_vector_type(8)));
typedef unsigned short u16x4 __attribute__((ext_vector_type(4)));

#define MFMA(a, b, c) __builtin_amdgcn_mfma_f32_16x16x32_bf16((a), (b), (c), 0, 0, 0)

// fine-grained barrier: 12 glds outstanding (3 buffers ahead), wait the
// oldest 4 (the buffer about to be read), never vmcnt(0). AITER pattern.
#define WAIT8_BARRIER() asm volatile("s_waitcnt vmcnt(8)\n\ts_barrier" ::: "memory")
#define LGKM_BARRIER()  asm volatile("s_waitcnt lgkmcnt(0)\n\ts_barrier" ::: "memory")
#define VM_DRAIN()      asm volatile("s_waitcnt vmcnt(0)" ::: "memory")

// B=8, T=2048, C=1024, H=64
#define TT 2048
#define CE 1024
#define HS 64

// ws layout (ushort elements unless noted)
#define WBT_E 0                   // [3][64 n][1024 k] bf16 (Wq scaled by log2e/32)
#define Q_E   196608              // [B*T][64] bf16
#define K_E   (Q_E + 1048576)
#define VT_E  (K_E + 1048576)     // [B][64 h][2048 t] bf16
#define PO_E  (VT_E + 1048576)    // [512 slots][64 row][64 h] bf16 partial O
#define PML_E (PO_E + 2097152)    // float [512][64 row][2] {m,l}

DEV unsigned short cvt_bf16(float f) {
    unsigned int u = __builtin_bit_cast(unsigned int, f);
    u += 0x7FFFu + ((u >> 16) & 1u);   // RNE (finite inputs)
    return (unsigned short)(u >> 16);
}

DEV float bf2f(unsigned short v) {
    unsigned int u = ((unsigned int)v) << 16;
    return __builtin_bit_cast(float, u);
}

DEV bf16x8 ld_bf8(const unsigned short* p) {
    union { u16x8 u; bf16x8 b; } v;
    v.u = *(const u16x8*)p;
    return v.b;
}

DEV bf16x8 as_bf8(u16x8 u) {
    union { u16x8 u; bf16x8 b; } v;
    v.u = u;
    return v.b;
}

// async global->LDS, 16B/lane; LDS dst is WAVE-UNIFORM base (+lane*16 by HW)
DEV void glds16(const void* g, void* l) {
    __builtin_amdgcn_global_load_lds(
        (const __attribute__((address_space(1))) void*)g,
        (__attribute__((address_space(3))) void*)l, 16, 0, 0);
}

// ---------------- kernel 1: W fp32 -> bf16 transposed [n][k] ----------------
__global__ __launch_bounds__(256) void wconv_kernel(
        const float* __restrict__ Wq, const float* __restrict__ Wk,
        const float* __restrict__ Wv, unsigned short* __restrict__ wbt) {
    __shared__ unsigned short Tr[64 * 72];
    const int blk = blockIdx.x;
    const int head = blk >> 4, kt = blk & 15;
    const int k0 = kt * 64;
    const float* W = (head == 0) ? Wq : ((head == 1) ? Wk : Wv);
    const float sc = (head == 0) ? 0.045084220027780106f : 1.0f;  // log2(e)/32
    const int t = threadIdx.x;
    const int rrow = t >> 4, c4 = (t & 15) * 4;
    for (int i = 0; i < 4; ++i) {
        int krow = rrow + i * 16;
        f32x4 f = *(const f32x4*)(W + (size_t)(k0 + krow) * 64 + c4);
        Tr[(c4 + 0) * 72 + krow] = cvt_bf16(f[0] * sc);
        Tr[(c4 + 1) * 72 + krow] = cvt_bf16(f[1] * sc);
        Tr[(c4 + 2) * 72 + krow] = cvt_bf16(f[2] * sc);
        Tr[(c4 + 3) * 72 + krow] = cvt_bf16(f[3] * sc);
    }
    __syncthreads();
    const int n = t >> 2, off = (t & 3) * 16;
    u16x8 a0 = *(const u16x8*)&Tr[n * 72 + off];
    u16x8 a1 = *(const u16x8*)&Tr[n * 72 + off + 8];
    unsigned short* dst = wbt + head * 65536 + n * 1024 + k0 + off;
    *(u16x8*)dst = a0;
    *(u16x8*)(dst + 8) = a1;
}

// ---------------- kernel 2: projection q,k = x@W; v transposed -> vt --------
// 512 blocks x 4 waves; 32 rows, 192 cols. K-step 32. FOUR statically
// distinct LDS buffer pairs (so LLVM's LDS-DMA alias check can prove the
// ds_reads don't touch in-flight DMA -> no compiler-inserted drain), glds
// issued 3 steps ahead, barrier = s_waitcnt vmcnt(8)+s_barrier.
__global__ __launch_bounds__(256) void proj_kernel(
        const float* __restrict__ x, const unsigned short* __restrict__ wbt,
        unsigned short* __restrict__ qws, unsigned short* __restrict__ kws,
        unsigned short* __restrict__ vtws) {
    __shared__ __align__(16) float Xt0[1024], Xt1[1024], Xt2[1024], Xt3[1024];
    __shared__ __align__(16) unsigned short Wt0[6144], Wt1[6144], Wt2[6144], Wt3[6144];
    __shared__ __align__(16) unsigned short TT2[64 * 48];  // v-transpose scratch

    const int t = threadIdx.x;
    const int lane = t & 63, w = t >> 6;
    const int quad = lane >> 4, c = lane & 15;
    const int wm = w & 1, wn = w >> 1;
    const int t0 = blockIdx.x * 32;

    // staging geometry (XOR swizzle: slot i holds content chunk i^key(row))
    const int srow = lane >> 3, scb = (lane & 7) ^ srow;   // x: 8x16B rows
    const float* xg = x + (size_t)(t0 + w * 8 + srow) * CE + scb * 4;
    const int wrow_lo = lane >> 2;                         // W: 4x16B rows
    const int wcb = (lane & 3) ^ (wrow_lo & 3);
    const unsigned short* wg0 = wbt + (size_t)((3 * w + 0) * 16 + wrow_lo) * 1024 + wcb * 8;
    const unsigned short* wg1 = wbt + (size_t)((3 * w + 1) * 16 + wrow_lo) * 1024 + wcb * 8;
    const unsigned short* wg2 = wbt + (size_t)((3 * w + 2) * 16 + wrow_lo) * 1024 + wcb * 8;

#define PSTAGE(XD, WD, ksn) \
    glds16(xg + (ksn), &XD[w * 256]); \
    glds16(wg0 + (ksn), &WD[(3 * w + 0) * 512]); \
    glds16(wg1 + (ksn), &WD[(3 * w + 1) * 512]); \
    glds16(wg2 + (ksn), &WD[(3 * w + 2) * 512]);

    f32x4 acc[6] = {};

    // prologue: stage steps 0,1,2 into buffers 0,1,2 (12 glds in flight)
    PSTAGE(Xt0, Wt0, 0)
    PSTAGE(Xt1, Wt1, 32)
    PSTAGE(Xt2, Wt2, 64)
    // no barrier: first PITER's WAIT8_BARRIER covers buffer 0 + syncs waves

    const int r = wm * 16 + c;           // A-frag row
    const int ck7 = c & 7, ck3 = c & 3;  // swizzle keys

#define PITER(step, XT, WT, XD, WD) { \
    WAIT8_BARRIER(); \
    f32x4 v0 = *(const f32x4*)&XT[r * 32 + (((2 * quad) ^ ck7) * 4)]; \
    f32x4 v1 = *(const f32x4*)&XT[r * 32 + (((2 * quad + 1) ^ ck7) * 4)]; \
    u16x8 ap; \
    _Pragma("unroll") for (int j = 0; j < 4; ++j) { \
        ap[j] = cvt_bf16(v0[j]); ap[4 + j] = cvt_bf16(v1[j]); } \
    bf16x8 af = as_bf8(ap); \
    _Pragma("unroll") for (int nt = 0; nt < 6; ++nt) { \
        bf16x8 bb = ld_bf8(&WT[(wn * 96 + nt * 16 + c) * 32 + ((quad ^ ck3) * 8)]); \
        acc[nt] = MFMA(af, bb, acc[nt]); } \
    const int ksn = (((step) + 3) & 31) * 32; \
    PSTAGE(XD, WD, ksn) }

    for (int s = 0; s < 32; s += 4) {
        PITER(s + 0, Xt0, Wt0, Xt3, Wt3)
        PITER(s + 1, Xt1, Wt1, Xt0, Wt0)
        PITER(s + 2, Xt2, Wt2, Xt1, Wt1)
        PITER(s + 3, Xt3, Wt3, Xt2, Wt2)
    }
#undef PITER
#undef PSTAGE

    // epilogue: q,k direct; v transposed via LDS (64 h x 32 t, stride 48)
    for (int nt = 0; nt < 6; ++nt) {
        int col = wn * 96 + nt * 16 + c;
        f32x4 a = acc[nt];
        for (int r4 = 0; r4 < 4; ++r4) {
            int row = wm * 16 + quad * 4 + r4;
            size_t tg = (size_t)(t0 + row);
            unsigned short hv = cvt_bf16(a[r4]);
            if (col < 64)       qws[tg * HS + col] = hv;
            else if (col < 128) kws[tg * HS + col - 64] = hv;
            else                TT2[(col - 128) * 48 + row] = hv;
        }
    }
    __syncthreads();   // full drain: also retires the tail dummy glds
    {
        int h = t >> 2, off = (t & 3) * 8;
        u16x8 v = *(const u16x8*)&TT2[h * 48 + off];
        int b = t0 >> 11, tl0 = t0 & 2047;
        *(u16x8*)(vtws + (size_t)(b * 64 + h) * TT + tl0 + off) = v;
    }
}

// ---------------- kernel 3: flash, 4 static buffers, glds 3 ahead -----------
// 512 blocks: sp=blk>>8; r8=blk&255; b=r8&7; qt=r8>>3 (sp1: 31-qt balance).
// Block = 64 q-rows; S^T = K.Q^T per wave (lane c owns q-row -> scalar
// softmax state). Pad-mask bias computed in prologue (bias kernel fused).
// Statically distinct K/V buffers; vmcnt(8) barrier; issue 3 iters ahead.
__global__ __launch_bounds__(256) void flash_kernel(
        const unsigned short* __restrict__ qws, const unsigned short* __restrict__ kws,
        const unsigned short* __restrict__ vtws, const int* __restrict__ pmask,
        unsigned short* __restrict__ pO, float* __restrict__ pml) {
    __shared__ __align__(16) unsigned short Kt0[4096], Kt1[4096], Kt2[4096], Kt3[4096];
    __shared__ __align__(16) unsigned short Vt0[4096], Vt1[4096], Vt2[4096], Vt3[4096];
    __shared__ __align__(16) unsigned short Ps[4][1152];  // per-wave P [q16][kv 64+8]
    __shared__ __align__(16) float Bs[1024];              // bias for <=16 iters

    const int t = threadIdx.x, blk = blockIdx.x;
    const int sp = blk >> 8, r8 = blk & 255, b = r8 & 7;
    int qt = r8 >> 3;
    if (sp) qt = 31 - qt;
    if (sp && qt == 0) return;               // empty second split
    const int half = (qt + 2) >> 1;
    const int jbeg = sp ? half : 0;
    const int jend = sp ? qt + 1 : half;
    const int niter = jend - jbeg;           // <= 16

    const int lane = t & 63, w = t >> 6;
    const int quad = lane >> 4, c = lane & 15;

    // staging geometry: instrs i0=2w, i1=2w+1 of 8; row = i*8 + (lane>>3)
    const int srow = lane >> 3, scb = (lane & 7) ^ srow;
    const unsigned short* kg0 = kws + (size_t)(b * TT + 2 * w * 8 + srow) * HS + scb * 8;
    const unsigned short* kg1 = kg0 + (size_t)8 * HS;
    const unsigned short* vg0 = vtws + (size_t)(b * 64 + 2 * w * 8 + srow) * TT + scb * 8;
    const unsigned short* vg1 = vg0 + (size_t)8 * TT;

#define FSTAGE(KD, VD, kv) \
    glds16(kg0 + (size_t)(kv) * HS, &KD[(2 * w + 0) * 512]); \
    glds16(kg1 + (size_t)(kv) * HS, &KD[(2 * w + 1) * 512]); \
    glds16(vg0 + (kv), &VD[(2 * w + 0) * 512]); \
    glds16(vg1 + (kv), &VD[(2 * w + 1) * 512]);

    // Q B-frag (n = qrow = c)
    bf16x8 qf[2];
#pragma unroll
    for (int kk = 0; kk < 2; ++kk)
        qf[kk] = ld_bf8(qws + (size_t)(b * TT + qt * 64 + w * 16 + c) * HS + kk * 32 + quad * 8);

    // fused bias: pad mask ints -> additive float bias in LDS
    {
        int bi = t * 4;
        if (bi < niter * 64) {
            i32x4 pmv = *(const i32x4*)(pmask + b * TT + jbeg * 64 + bi);
            f32x4 bvv;
#pragma unroll
            for (int j = 0; j < 4; ++j) bvv[j] = pmv[j] ? 0.0f : -1e30f;
            *(f32x4*)&Bs[bi] = bvv;
        }
    }

    // prologue: stage iters jbeg..jbeg+2 (clamped) into buffers 0,1,2
    {
        int j1 = (jbeg + 1 > jend - 1) ? jend - 1 : jbeg + 1;
        int j2 = (jbeg + 2 > jend - 1) ? jend - 1 : jbeg + 2;
        FSTAGE(Kt0, Vt0, jbeg * 64)
        FSTAGE(Kt1, Vt1, j1 * 64)
        FSTAGE(Kt2, Vt2, j2 * 64)
    }
    LGKM_BARRIER();   // Bs visible; glds handled by first WAIT8_BARRIER

    f32x4 o[4] = {};
    float m_run = -1e30f, l_run = 0.0f;
    const int ck7 = c & 7;

#define FITER(u, KT, VT, KD, VD) \
    if (j0 + (u) < jend) { \
        const int j = j0 + (u); \
        WAIT8_BARRIER(); \
        f32x4 bv[4]; \
        _Pragma("unroll") for (int nt = 0; nt < 4; ++nt) \
            bv[nt] = *(const f32x4*)&Bs[(j - jbeg) * 64 + nt * 16 + quad * 4]; \
        f32x4 s4[4] = {}; \
        _Pragma("unroll") for (int kk = 0; kk < 2; ++kk) \
        _Pragma("unroll") for (int nt = 0; nt < 4; ++nt) { \
            bf16x8 ka = ld_bf8(&KT[(nt * 16 + c) * 64 + (((kk * 4 + quad) ^ ck7) * 8)]); \
            s4[nt] = MFMA(ka, qf[kk], s4[nt]); } \
        if (j == qt) { \
            const int qrl = w * 16 + c; \
            _Pragma("unroll") for (int nt = 0; nt < 4; ++nt) \
            _Pragma("unroll") for (int r = 0; r < 4; ++r) { \
                int kvl = nt * 16 + quad * 4 + r; \
                s4[nt][r] = (kvl > qrl) ? -1e30f : (s4[nt][r] + bv[nt][r]); } \
        } else { \
            _Pragma("unroll") for (int nt = 0; nt < 4; ++nt) \
            _Pragma("unroll") for (int r = 0; r < 4; ++r) s4[nt][r] += bv[nt][r]; } \
        float mx = s4[0][0]; \
        _Pragma("unroll") for (int nt = 0; nt < 4; ++nt) \
        _Pragma("unroll") for (int r = 0; r < 4; ++r) mx = fmaxf(mx, s4[nt][r]); \
        mx = fmaxf(mx, __shfl_xor(mx, 16, 64)); \
        mx = fmaxf(mx, __shfl_xor(mx, 32, 64)); \
        float mnew = fmaxf(m_run, mx); \
        float al = exp2f(m_run - mnew); \
        m_run = mnew; \
        _Pragma("unroll") for (int nt = 0; nt < 4; ++nt) \
        _Pragma("unroll") for (int r = 0; r < 4; ++r) s4[nt][r] = exp2f(s4[nt][r] - mnew); \
        float rs = 0.0f; \
        _Pragma("unroll") for (int nt = 0; nt < 4; ++nt) \
            rs += (s4[nt][0] + s4[nt][1]) + (s4[nt][2] + s4[nt][3]); \
        rs += __shfl_xor(rs, 16, 64); \
        rs += __shfl_xor(rs, 32, 64); \
        l_run = l_run * al + rs; \
        _Pragma("unroll") for (int ht = 0; ht < 4; ++ht) \
        _Pragma("unroll") for (int r = 0; r < 4; ++r) o[ht][r] *= al; \
        _Pragma("unroll") for (int nt = 0; nt < 4; ++nt) { \
            u16x4 pk; \
            _Pragma("unroll") for (int r = 0; r < 4; ++r) pk[r] = cvt_bf16(s4[nt][r]); \
            *(u16x4*)&Ps[w][c * 72 + nt * 16 + quad * 4] = pk; } \
        bf16x8 p0 = ld_bf8(&Ps[w][c * 72 + quad * 8]); \
        bf16x8 p1 = ld_bf8(&Ps[w][c * 72 + 32 + quad * 8]); \
        _Pragma("unroll") for (int kk = 0; kk < 2; ++kk) { \
            bf16x8 pa = kk ? p1 : p0; \
            _Pragma("unroll") for (int ht = 0; ht < 4; ++ht) { \
                bf16x8 va = ld_bf8(&VT[(ht * 16 + c) * 64 + (((kk * 4 + quad) ^ ck7) * 8)]); \
                o[ht] = MFMA(va, pa, o[ht]); } } \
        int jn = j + 3; if (jn > jend - 1) jn = jend - 1; \
        FSTAGE(KD, VD, jn * 64) \
    }

    for (int j0 = jbeg; j0 < jend; j0 += 4) {
        FITER(0, Kt0, Vt0, Kt3, Vt3)
        FITER(1, Kt1, Vt1, Kt0, Vt0)
        FITER(2, Kt2, Vt2, Kt1, Vt1)
        FITER(3, Kt3, Vt3, Kt2, Vt2)
    }
#undef FITER
#undef FSTAGE

    VM_DRAIN();   // retire tail glds before LDS dealloc at endpgm

    // ---- store partials: slot = blk; pO [slot][row 64][h 64] ----
    unsigned short* po = pO + (size_t)blk * 4096;
#pragma unroll
    for (int ht = 0; ht < 4; ++ht) {
        u16x4 pk;
#pragma unroll
        for (int r = 0; r < 4; ++r) pk[r] = cvt_bf16(o[ht][r]);
        *(u16x4*)(po + (w * 16 + c) * 64 + ht * 16 + quad * 4) = pk;
    }
    if (quad == 0) {
        pml[(size_t)blk * 128 + (w * 16 + c) * 2] = m_run;
        pml[(size_t)blk * 128 + (w * 16 + c) * 2 + 1] = l_run;
    }
}

// ---------------- kernel 4: combine 2 splits -> final output ----------------
// 256 blocks (b,qt) x 256 thr; slot0 = qt*8+b, slot1 = 256 + (31-qt)*8 + b.
__global__ __launch_bounds__(256) void combine_kernel(
        const unsigned short* __restrict__ pO, const float* __restrict__ pml,
        float* __restrict__ out) {
    const int blk = blockIdx.x;
    const int qt = blk >> 3, b = blk & 7;
    const int s0 = qt * 8 + b, s1 = 256 + (31 - qt) * 8 + b;
    const bool two = (qt > 0);
    const int t = threadIdx.x, h = t & 63, rg = t >> 6;
    for (int i = 0; i < 16; ++i) {
        int row = rg + i * 4;
        float m0 = pml[(size_t)s0 * 128 + row * 2];
        float l0 = pml[(size_t)s0 * 128 + row * 2 + 1];
        float o0 = bf2f(pO[(size_t)s0 * 4096 + row * 64 + h]);
        float num, den;
        if (two) {
            float m1 = pml[(size_t)s1 * 128 + row * 2];
            float l1 = pml[(size_t)s1 * 128 + row * 2 + 1];
            float o1 = bf2f(pO[(size_t)s1 * 4096 + row * 64 + h]);
            float M = fmaxf(m0, m1);
            float w0 = exp2f(m0 - M), w1 = exp2f(m1 - M);
            num = o0 * w0 + o1 * w1;
            den = l0 * w0 + l1 * w1;
        } else {
            num = o0; den = l0;
        }
        out[(size_t)(b * TT + qt * 64 + row) * HS + h] = num / den;
    }
}

extern "C" void kernel_launch(void* const* d_in, const int* in_sizes, int n_in,
                              void* d_out, int out_size, void* d_ws, size_t ws_size,
                              hipStream_t stream) {
    const float* x  = (const float*)d_in[0];
    const int* pm   = (const int*)d_in[1];
    const float* Wq = (const float*)d_in[2];
    const float* Wk = (const float*)d_in[3];
    const float* Wv = (const float*)d_in[4];
    float* out = (float*)d_out;

    unsigned short* wsu  = (unsigned short*)d_ws;
    unsigned short* wbt  = wsu + WBT_E;
    unsigned short* qws  = wsu + Q_E;
    unsigned short* kws  = wsu + K_E;
    unsigned short* vtws = wsu + VT_E;
    unsigned short* pO   = wsu + PO_E;
    float* pml           = (float*)(wsu + PML_E);

    wconv_kernel<<<48, 256, 0, stream>>>(Wq, Wk, Wv, wbt);
    proj_kernel<<<512, 256, 0, stream>>>(x, wbt, qws, kws, vtws);
    flash_kernel<<<512, 256, 0, stream>>>(qws, kws, vtws, pm, pO, pml);
    combine_kernel<<<256, 256, 0, stream>>>(pO, pml, out);
}